// Round 3
// baseline (353.814 us; speedup 1.0000x reference)
//
#include <hip/hip_runtime.h>

#define S_LEN 2048
#define DIMSZ 3072
#define NHEAD 24
#define HDIM 128
#define NQKV 9216
#define QSCALE 0.08838834764831845f
#define FMAX 12.0f

typedef unsigned short u16;
typedef unsigned int u32;
typedef __attribute__((ext_vector_type(8))) short short8;
typedef __attribute__((ext_vector_type(4))) float f32x4;

__device__ __forceinline__ u16 f2bf(float f) {
    u32 u = __float_as_uint(f);
    u32 r = (u + 0x7fffu + ((u >> 16) & 1u)) >> 16;
    return (u16)r;
}

__device__ __forceinline__ void lds16(u16* lds, const u16* g) {
    __builtin_amdgcn_global_load_lds((const __attribute__((address_space(1))) u32*)g,
                                     (__attribute__((address_space(3))) u32*)lds, 16, 0, 0);
}

// ---------------- conversion kernels ----------------
__global__ void k_f2bf4(const float4* __restrict__ src, u16* __restrict__ dst, int n4) {
    int i = blockIdx.x * blockDim.x + threadIdx.x;
    if (i >= n4) return;
    float4 v = src[i];
    u32 lo = (u32)f2bf(v.x) | ((u32)f2bf(v.y) << 16);
    u32 hi = (u32)f2bf(v.z) | ((u32)f2bf(v.w) << 16);
    uint2 p; p.x = lo; p.y = hi;
    *(uint2*)(dst + (size_t)i * 4) = p;
}

__global__ void k_bias(const float* __restrict__ bq, const float* __restrict__ bk,
                       const float* __restrict__ bv, float* __restrict__ bias) {
    int i = blockIdx.x * 256 + threadIdx.x;
    if (i < 3072) bias[i] = bq[i];
    else if (i < 6144) bias[i] = bk[i - 3072];
    else if (i < 9216) bias[i] = bv[i - 6144];
}

// ---------------- QKV GEMM (256x256 tile, 8-phase counted-vmcnt pipeline) ----------------
// C[m][n] = sum_k A[m][k]*W[n][k] + bias[n]
// A: [2048][3072] bf16, W: [9216][3072] bf16, C: [2048][9216] f32
// 8 waves (2M x 4N), per-wave 128x64 output. K-tile = BK=64, 48 tiles.
// LDS: 9 rotating half-tile slots (16 KiB = 128 rows x 64 cols bf16, chunk^=row&7 swizzle).
// Half-tile order per tile T: H=4T+{0,1}=A halves, 4T+{2,3}=B halves. Stage-ahead d=5 phases.
__global__ __launch_bounds__(512, 2) void k_gemm(const u16* __restrict__ A, const u16* __restrict__ W,
                                                 const float* __restrict__ bias, float* __restrict__ C) {
    __shared__ __align__(16) u16 lds[9 * 8192]; // 144 KiB
    const int tid = threadIdx.x, wave = tid >> 6, lane = tid & 63;
    const int bm = blockIdx.x & 7, bn = blockIdx.x >> 3; // 8 XCDs x 36: XCD shares A-panel
    const int wr = wave >> 2, wc = wave & 3;
    const int frow = lane & 15, fk = lane >> 4;

    const u16* baseA = A + (size_t)(bm * 256) * DIMSZ;
    const u16* baseW = W + (size_t)(bn * 256) * DIMSZ;

    // stage half-tile: slot s, type (0/1 = A half0/1, 2/3 = W half0/1), k-tile kt
    auto stage = [&](int s, int type, int kt) {
        const u16* mb = (type < 2) ? (baseA + (size_t)((type & 1) * 128) * DIMSZ)
                                   : (baseW + (size_t)((type & 1) * 128) * DIMSZ);
#pragma unroll
        for (int j = 0; j < 2; ++j) {
            int flat = j * 512 + tid;
            int row = flat >> 3, ch = flat & 7;
            lds16(lds + s * 8192 + flat * 8,
                  mb + (size_t)row * DIMSZ + kt * 64 + ((ch ^ (row & 7)) * 8));
        }
    };

    // prologue: halves 0..4 (tile0 complete + tile1 A-half0)
    stage(0, 0, 0); stage(1, 1, 0); stage(2, 2, 0); stage(3, 3, 0); stage(4, 0, 1);
    asm volatile("s_waitcnt vmcnt(2)"); // halves 0..3 landed
    __builtin_amdgcn_s_barrier();

    f32x4 acc[8][4] = {};
    int sA = wr;            // slot of A-half(wr), tile 0
    int sB = 2 + (wc >> 1); // slot of B-half(wc>>1), tile 0
    int sS = 5;             // stage slot for H = P+5

    for (int T = 0; T < 48; ++T) {
        short8 bf[4][2];
#pragma unroll
        for (int q = 0; q < 4; ++q) {
            // ds_read this phase's A quadrant (mf = 2q, 2q+1)
            short8 af[2][2];
#pragma unroll
            for (int i = 0; i < 2; ++i) {
                int lrow = (2 * q + i) * 16 + frow;
#pragma unroll
                for (int ks = 0; ks < 2; ++ks)
                    af[i][ks] = *(const short8*)&lds[sA * 8192 + lrow * 64 + (((ks * 4 + fk) ^ (frow & 7)) * 8)];
            }
            if (q == 0) { // B fragments once per tile
#pragma unroll
                for (int nf = 0; nf < 4; ++nf) {
                    int lrow = (wc & 1) * 64 + nf * 16 + frow;
#pragma unroll
                    for (int ks = 0; ks < 2; ++ks)
                        bf[nf][ks] = *(const short8*)&lds[sB * 8192 + lrow * 64 + (((ks * 4 + fk) ^ (frow & 7)) * 8)];
                }
            }
            // stage half H = 4T+q+5: type=(q+1)&3, kt = T + (q==3 ? 2 : 1)
            if (4 * T + q + 5 < 192) {
                stage(sS, (q + 1) & 3, T + (q == 3 ? 2 : 1));
                sS = (sS + 1 == 9) ? 0 : sS + 1;
            }
            if (q == 3) { // protect tile T+1's halves (counted, never 0 mid-loop)
                if (T < 46) asm volatile("s_waitcnt vmcnt(2)");
                else if (T == 46) asm volatile("s_waitcnt vmcnt(0)");
            }
            __builtin_amdgcn_s_barrier();
            __builtin_amdgcn_s_setprio(1);
#pragma unroll
            for (int i = 0; i < 2; ++i)
#pragma unroll
                for (int nf = 0; nf < 4; ++nf)
#pragma unroll
                    for (int ks = 0; ks < 2; ++ks)
                        acc[2 * q + i][nf] =
                            __builtin_amdgcn_mfma_f32_16x16x32_bf16(af[i][ks], bf[nf][ks], acc[2 * q + i][nf], 0, 0, 0);
            __builtin_amdgcn_s_setprio(0);
            __builtin_amdgcn_s_barrier();
        }
        sA += 4; if (sA >= 9) sA -= 9;
        sB += 4; if (sB >= 9) sB -= 9;
    }

    // epilogue: C = acc + bias
#pragma unroll
    for (int mf = 0; mf < 8; ++mf) {
#pragma unroll
        for (int nf = 0; nf < 4; ++nf) {
            int n = bn * 256 + wc * 64 + nf * 16 + frow;
            float b = bias[n];
#pragma unroll
            for (int i = 0; i < 4; ++i) {
                int m = bm * 256 + wr * 128 + mf * 16 + fk * 4 + i;
                C[(size_t)m * NQKV + n] = acc[mf][nf][i] + b;
            }
        }
    }
}

// ---------------- postprocess: RMSNorm + RoPE + layout ----------------
__global__ void k_post(const float* __restrict__ qkv, const float* __restrict__ nw_q,
                       const float* __restrict__ nw_k, const float* __restrict__ cosT,
                       const float* __restrict__ sinT, u16* __restrict__ Qb,
                       u16* __restrict__ Kb, u16* __restrict__ Vt) {
    const int wave = threadIdx.x >> 6, lane = threadIdx.x & 63;
    const int s = blockIdx.x * 4 + wave;
    const int h = blockIdx.y;
    const int d0 = 2 * lane, d1 = 2 * lane + 1;
    const float c = cosT[s * HDIM + d0], sn = sinT[s * HDIM + d0];
    // Q
    {
        const float* row = qkv + (size_t)s * NQKV + h * HDIM;
        float x0 = row[d0], x1 = row[d1];
        float ss = x0 * x0 + x1 * x1;
        for (int m = 1; m < 64; m <<= 1) ss += __shfl_xor(ss, m);
        float r = rsqrtf(ss * (1.0f / 128.0f) + 1e-6f);
        x0 *= r * nw_q[d0]; x1 *= r * nw_q[d1];
        float o0 = (x0 * c - x1 * sn) * QSCALE;
        float o1 = (x1 * c + x0 * sn) * QSCALE;
        u32 p = (u32)f2bf(o0) | ((u32)f2bf(o1) << 16);
        *(u32*)&Qb[((size_t)h * S_LEN + s) * HDIM + d0] = p;
    }
    // K
    {
        const float* row = qkv + (size_t)s * NQKV + 3072 + h * HDIM;
        float x0 = row[d0], x1 = row[d1];
        float ss = x0 * x0 + x1 * x1;
        for (int m = 1; m < 64; m <<= 1) ss += __shfl_xor(ss, m);
        float r = rsqrtf(ss * (1.0f / 128.0f) + 1e-6f);
        x0 *= r * nw_k[d0]; x1 *= r * nw_k[d1];
        float o0 = x0 * c - x1 * sn;
        float o1 = x1 * c + x0 * sn;
        u32 p = (u32)f2bf(o0) | ((u32)f2bf(o1) << 16);
        *(u32*)&Kb[((size_t)h * S_LEN + s) * HDIM + d0] = p;
    }
    // V (transposed)
    {
        const float* row = qkv + (size_t)s * NQKV + 6144 + h * HDIM;
        Vt[((size_t)h * HDIM + d0) * S_LEN + s] = f2bf(row[d0]);
        Vt[((size_t)h * HDIM + d1) * S_LEN + s] = f2bf(row[d1]);
    }
}

// ---------------- flash attention (no mask, fixed-max softmax) ----------------
__global__ __launch_bounds__(256, 2) void k_attn(const u16* __restrict__ Qb, const u16* __restrict__ Kb,
                                                 const u16* __restrict__ Vt, float* __restrict__ out) {
    __shared__ __align__(16) u16 Ks[2][64 * 128];   // [key][d], chunk ^= row&15
    __shared__ __align__(16) u16 Vs[2][128 * 64];   // [d][key], chunk ^= row&7
    __shared__ __align__(16) u16 Ps[4][32 * 64];    // per-wave P, chunk ^= row&7
    const int wave = threadIdx.x >> 6, lane = threadIdx.x & 63;
    const int wg = (blockIdx.x & 7) * 48 + (blockIdx.x >> 3);
    const int h = wg >> 4, qb = wg & 15;
    const int frow = lane & 15, fk = lane >> 4;

    short8 qf[2][4];
#pragma unroll
    for (int qg = 0; qg < 2; ++qg) {
        const u16* qbase = Qb + ((size_t)h * S_LEN + qb * 128 + wave * 32 + qg * 16 + frow) * HDIM + fk * 8;
#pragma unroll
        for (int ks = 0; ks < 4; ++ks) qf[qg][ks] = *(const short8*)(qbase + ks * 32);
    }

    f32x4 o[2][8] = {};
    float l_p[2][4] = {};

#define STAGE(buf, kt)                                                                       \
    {                                                                                        \
        _Pragma("unroll") for (int c = 0; c < 4; ++c) {                                      \
            int fi = (wave * 4 + c) * 64 + lane;                                             \
            {                                                                                \
                int r = fi >> 4, ch = fi & 15;                                               \
                lds16(Ks[buf] + (wave * 4 + c) * 512,                                        \
                      Kb + ((size_t)h * S_LEN + (kt) * 64 + r) * HDIM + ((ch ^ (r & 15)) * 8)); \
            }                                                                                \
            {                                                                                \
                int r = fi >> 3, ch = fi & 7;                                                \
                lds16(Vs[buf] + (wave * 4 + c) * 512,                                        \
                      Vt + ((size_t)h * HDIM + r) * S_LEN + (kt) * 64 + ((ch ^ (r & 7)) * 8)); \
            }                                                                                \
        }                                                                                    \
    }

    STAGE(0, 0);
    __syncthreads();
    int cur = 0;

    for (int kt = 0; kt < S_LEN / 64; ++kt) {
        if (kt + 1 < S_LEN / 64) STAGE(cur ^ 1, kt + 1);
        f32x4 sacc[2][4] = {};
#pragma unroll
        for (int nf = 0; nf < 4; ++nf) {
#pragma unroll
            for (int ks = 0; ks < 4; ++ks) {
                short8 kf = *(const short8*)&Ks[cur][(nf * 16 + frow) * 128 + (((ks * 4 + fk) ^ frow) & 15) * 8];
#pragma unroll
                for (int qg = 0; qg < 2; ++qg)
                    sacc[qg][nf] = __builtin_amdgcn_mfma_f32_16x16x32_bf16(qf[qg][ks], kf, sacc[qg][nf], 0, 0, 0);
            }
        }
#pragma unroll
        for (int qg = 0; qg < 2; ++qg)
#pragma unroll
            for (int nf = 0; nf < 4; ++nf)
#pragma unroll
                for (int i = 0; i < 4; ++i) {
                    float p = __expf(sacc[qg][nf][i] - FMAX);
                    l_p[qg][i] += p;
                    int row = qg * 16 + fk * 4 + i, col = nf * 16 + frow;
                    Ps[wave][row * 64 + (((col >> 3) ^ (row & 7)) << 3) + (col & 7)] = f2bf(p);
                }
#pragma unroll
        for (int ks = 0; ks < 2; ++ks) {
            short8 pf[2];
#pragma unroll
            for (int qg = 0; qg < 2; ++qg)
                pf[qg] = *(const short8*)&Ps[wave][(qg * 16 + frow) * 64 + (((ks * 4 + fk) ^ (frow & 7)) & 7) * 8];
#pragma unroll
            for (int nf8 = 0; nf8 < 8; ++nf8) {
                short8 vf = *(const short8*)&Vs[cur][(nf8 * 16 + frow) * 64 + (((ks * 4 + fk) ^ (frow & 7)) & 7) * 8];
#pragma unroll
                for (int qg = 0; qg < 2; ++qg)
                    o[qg][nf8] = __builtin_amdgcn_mfma_f32_16x16x32_bf16(pf[qg], vf, o[qg][nf8], 0, 0, 0);
            }
        }
        __syncthreads();
        cur ^= 1;
    }
#undef STAGE

#pragma unroll
    for (int msk = 1; msk < 16; msk <<= 1)
#pragma unroll
        for (int qg = 0; qg < 2; ++qg)
#pragma unroll
            for (int i = 0; i < 4; ++i) l_p[qg][i] += __shfl_xor(l_p[qg][i], msk);

#pragma unroll
    for (int qg = 0; qg < 2; ++qg)
#pragma unroll
        for (int nf8 = 0; nf8 < 8; ++nf8)
#pragma unroll
            for (int i = 0; i < 4; ++i) {
                int srow = qb * 128 + wave * 32 + qg * 16 + fk * 4 + i;
                out[(size_t)srow * DIMSZ + h * HDIM + nf8 * 16 + frow] = o[qg][nf8][i] / l_p[qg][i];
            }
}

// ---------------- launch ----------------
extern "C" void kernel_launch(void* const* d_in, const int* in_sizes, int n_in,
                              void* d_out, int out_size, void* d_ws, size_t ws_size,
                              hipStream_t stream) {
    const float* hs = (const float*)d_in[0];
    const float* wq = (const float*)d_in[1];
    const float* bq = (const float*)d_in[2];
    const float* wk = (const float*)d_in[3];
    const float* bk = (const float*)d_in[4];
    const float* wv = (const float*)d_in[5];
    const float* bv = (const float*)d_in[6];
    const float* nq = (const float*)d_in[7];
    const float* nk = (const float*)d_in[8];
    const float* cosT = (const float*)d_in[9];
    const float* sinT = (const float*)d_in[10];
    float* out = (float*)d_out;

    char* ws = (char*)d_ws;
    u16* hs_b = (u16*)(ws + 0);                  // 12,582,912 B
    u16* w_b = (u16*)(ws + 12582912);            // 56,623,104 B
    float* bias = (float*)(ws + 69206016);       // 36,864 B
    float* qkv = (float*)(ws + 69242880);        // 75,497,472 B
    u16* Qb = (u16*)(ws + 144740352);            // 12,582,912 B
    u16* Kb = (u16*)(ws + 157323264);            // 12,582,912 B
    u16* Vt = (u16*)(ws + 169906176);            // 12,582,912 B

    k_f2bf4<<<6144, 256, 0, stream>>>((const float4*)hs, hs_b, 1572864);
    k_f2bf4<<<9216, 256, 0, stream>>>((const float4*)wq, w_b, 2359296);
    k_f2bf4<<<9216, 256, 0, stream>>>((const float4*)wk, w_b + 9437184, 2359296);
    k_f2bf4<<<9216, 256, 0, stream>>>((const float4*)wv, w_b + 18874368, 2359296);
    k_bias<<<36, 256, 0, stream>>>(bq, bk, bv, bias);

    // QKV projection: 288 blocks = 8 (bm, one per XCD) x 36 (bn)
    k_gemm<<<dim3(288), 512, 0, stream>>>(hs_b, w_b, bias, qkv);

    k_post<<<dim3(512, 24), 256, 0, stream>>>(qkv, nq, nk, cosT, sinT, Qb, Kb, Vt);

    k_attn<<<dim3(384), 256, 0, stream>>>(Qb, Kb, Vt, out);
}

// Round 4
// 352.024 us; speedup vs baseline: 1.0051x; 1.0051x over previous
//
#include <hip/hip_runtime.h>

#define S_LEN 2048
#define DIMSZ 3072
#define NHEAD 24
#define HDIM 128
#define NQKV 9216
#define QSCALE 0.08838834764831845f
#define FMAX 12.0f

typedef unsigned short u16;
typedef unsigned int u32;
typedef __attribute__((ext_vector_type(8))) short short8;
typedef __attribute__((ext_vector_type(4))) float f32x4;

__device__ __forceinline__ u16 f2bf(float f) {
    u32 u = __float_as_uint(f);
    u32 r = (u + 0x7fffu + ((u >> 16) & 1u)) >> 16;
    return (u16)r;
}

__device__ __forceinline__ void lds16(u16* lds, const u16* g) {
    __builtin_amdgcn_global_load_lds((const __attribute__((address_space(1))) u32*)g,
                                     (__attribute__((address_space(3))) u32*)lds, 16, 0, 0);
}

// ---------------- conversion kernels ----------------
__global__ void k_f2bf4(const float4* __restrict__ src, u16* __restrict__ dst, int n4) {
    int i = blockIdx.x * blockDim.x + threadIdx.x;
    if (i >= n4) return;
    float4 v = src[i];
    u32 lo = (u32)f2bf(v.x) | ((u32)f2bf(v.y) << 16);
    u32 hi = (u32)f2bf(v.z) | ((u32)f2bf(v.w) << 16);
    uint2 p; p.x = lo; p.y = hi;
    *(uint2*)(dst + (size_t)i * 4) = p;
}

// ---------------- QKV GEMM: C[m][n] = sum_k A[m][k]*W[n][k]  (bias added in k_post) ----
// 256x256 tile, BK=64, 8 waves (2M x 4N), per-wave 128x64.
// Front-loaded ds_reads (buffer freed early) + stage tile T+2 into SAME buffer at
// phases 1(B)/3(A) -> 5-7 phase prefetch lead. One counted vmcnt(8) per tile.
// NSEG=2: split-K (576 blocks, 24 K-tiles each, f32 partials). NSEG=1: 288 blocks, 48 tiles.
template <int NSEG>
__global__ __launch_bounds__(512, 2) void k_gemm(const u16* __restrict__ A, const u16* __restrict__ W,
                                                 float* __restrict__ C) {
    constexpr int NT = (NSEG == 2) ? 24 : 48;
    __shared__ __align__(16) u16 lds[2][2][256 * 64]; // [buf][A/B][row*64+col], 128 KiB
    const int tid = threadIdx.x, wave = tid >> 6, lane = tid & 63;
    const int g = blockIdx.x;
    const int bm = g & 7, inner = g >> 3;       // bm tied to XCD for A-panel L2 reuse
    const int bn = inner % 36, kseg = inner / 36;
    const int wr = wave >> 2, wc = wave & 3;
    const int frow = lane & 15, fk = lane >> 4;
    const u16* baseA = A + (size_t)(bm * 256) * DIMSZ + kseg * (NT * 64);
    const u16* baseW = W + (size_t)(bn * 256) * DIMSZ + kseg * (NT * 64);
    float* Cp = C + (size_t)kseg * S_LEN * NQKV;

    auto stageA = [&](int b, int kt) {
#pragma unroll
        for (int j = 0; j < 4; ++j) {
            int flat = j * 512 + tid, row = flat >> 3, ch = flat & 7;
            lds16(&lds[b][0][flat * 8], baseA + (size_t)row * DIMSZ + kt * 64 + ((ch ^ (row & 7)) * 8));
        }
    };
    auto stageB = [&](int b, int kt) {
#pragma unroll
        for (int j = 0; j < 4; ++j) {
            int flat = j * 512 + tid, row = flat >> 3, ch = flat & 7;
            lds16(&lds[b][1][flat * 8], baseW + (size_t)row * DIMSZ + kt * 64 + ((ch ^ (row & 7)) * 8));
        }
    };

    // prologue: tiles 0,1
    stageA(0, 0); stageB(0, 0); stageA(1, 1); stageB(1, 1);
    asm volatile("s_waitcnt vmcnt(8)"); // tile 0 landed
    __builtin_amdgcn_s_barrier();

    f32x4 acc[8][4] = {};
    for (int T = 0; T < NT; ++T) {
        const int b = T & 1;
        const u16* LA = lds[b][0];
        const u16* LB = lds[b][1];
        short8 af[8][2], bf[4][2];
        // ---- phase 0: read A(mf0-3) + all B; MFMA quadrant 0 (af0,af1) ----
#pragma unroll
        for (int mf = 0; mf < 4; ++mf) {
            int lrow = wr * 128 + mf * 16 + frow;
#pragma unroll
            for (int ks = 0; ks < 2; ++ks)
                af[mf][ks] = *(const short8*)&LA[lrow * 64 + (((ks * 4 + fk) ^ (frow & 7)) * 8)];
        }
#pragma unroll
        for (int nf = 0; nf < 4; ++nf) {
            int lrow = wc * 64 + nf * 16 + frow;
#pragma unroll
            for (int ks = 0; ks < 2; ++ks)
                bf[nf][ks] = *(const short8*)&LB[lrow * 64 + (((ks * 4 + fk) ^ (frow & 7)) * 8)];
        }
        __builtin_amdgcn_s_barrier();
        __builtin_amdgcn_s_setprio(1);
#pragma unroll
        for (int i = 0; i < 2; ++i)
#pragma unroll
            for (int nf = 0; nf < 4; ++nf)
#pragma unroll
                for (int ks = 0; ks < 2; ++ks)
                    acc[i][nf] = __builtin_amdgcn_mfma_f32_16x16x32_bf16(af[i][ks], bf[nf][ks], acc[i][nf], 0, 0, 0);
        __builtin_amdgcn_s_setprio(0);
        __builtin_amdgcn_s_barrier();
        // ---- phase 1: read A(mf4,5); stage B(T+2); MFMA quadrant 1 (af2,af3) ----
#pragma unroll
        for (int mf = 4; mf < 6; ++mf) {
            int lrow = wr * 128 + mf * 16 + frow;
#pragma unroll
            for (int ks = 0; ks < 2; ++ks)
                af[mf][ks] = *(const short8*)&LA[lrow * 64 + (((ks * 4 + fk) ^ (frow & 7)) * 8)];
        }
        if (T < NT - 2) stageB(b, T + 2);
        __builtin_amdgcn_s_barrier();
        __builtin_amdgcn_s_setprio(1);
#pragma unroll
        for (int i = 2; i < 4; ++i)
#pragma unroll
            for (int nf = 0; nf < 4; ++nf)
#pragma unroll
                for (int ks = 0; ks < 2; ++ks)
                    acc[i][nf] = __builtin_amdgcn_mfma_f32_16x16x32_bf16(af[i][ks], bf[nf][ks], acc[i][nf], 0, 0, 0);
        __builtin_amdgcn_s_setprio(0);
        __builtin_amdgcn_s_barrier();
        // ---- phase 2: read A(mf6,7); MFMA quadrant 2 (af4,af5) ----
#pragma unroll
        for (int mf = 6; mf < 8; ++mf) {
            int lrow = wr * 128 + mf * 16 + frow;
#pragma unroll
            for (int ks = 0; ks < 2; ++ks)
                af[mf][ks] = *(const short8*)&LA[lrow * 64 + (((ks * 4 + fk) ^ (frow & 7)) * 8)];
        }
        __builtin_amdgcn_s_barrier();
        __builtin_amdgcn_s_setprio(1);
#pragma unroll
        for (int i = 4; i < 6; ++i)
#pragma unroll
            for (int nf = 0; nf < 4; ++nf)
#pragma unroll
                for (int ks = 0; ks < 2; ++ks)
                    acc[i][nf] = __builtin_amdgcn_mfma_f32_16x16x32_bf16(af[i][ks], bf[nf][ks], acc[i][nf], 0, 0, 0);
        __builtin_amdgcn_s_setprio(0);
        __builtin_amdgcn_s_barrier();
        // ---- phase 3: stage A(T+2); counted vmcnt; MFMA quadrant 3 (af6,af7) ----
        if (T < NT - 2) {
            stageA(b, T + 2);
            asm volatile("s_waitcnt vmcnt(8)"); // tile T+1's 8 loads landed
        } else if (T == NT - 2) {
            asm volatile("s_waitcnt vmcnt(0)"); // tail drain
        }
        __builtin_amdgcn_s_barrier();
        __builtin_amdgcn_s_setprio(1);
#pragma unroll
        for (int i = 6; i < 8; ++i)
#pragma unroll
            for (int nf = 0; nf < 4; ++nf)
#pragma unroll
                for (int ks = 0; ks < 2; ++ks)
                    acc[i][nf] = __builtin_amdgcn_mfma_f32_16x16x32_bf16(af[i][ks], bf[nf][ks], acc[i][nf], 0, 0, 0);
        __builtin_amdgcn_s_setprio(0);
        __builtin_amdgcn_s_barrier();
    }

    // epilogue: f32 partials (no bias)
#pragma unroll
    for (int mf = 0; mf < 8; ++mf) {
#pragma unroll
        for (int nf = 0; nf < 4; ++nf) {
            int n = bn * 256 + wc * 64 + nf * 16 + frow;
#pragma unroll
            for (int i = 0; i < 4; ++i) {
                int m = bm * 256 + wr * 128 + mf * 16 + fk * 4 + i;
                Cp[(size_t)m * NQKV + n] = acc[mf][nf][i];
            }
        }
    }
}

// ---------------- postprocess: partial-sum + bias + RMSNorm + RoPE + layout ----------------
template <int NSEG>
__global__ void k_post(const float* __restrict__ qkv, const float* __restrict__ nw_q,
                       const float* __restrict__ nw_k, const float* __restrict__ bq,
                       const float* __restrict__ bk, const float* __restrict__ bv,
                       const float* __restrict__ cosT, const float* __restrict__ sinT,
                       u16* __restrict__ Qb, u16* __restrict__ Kb, u16* __restrict__ Vt) {
    const int wave = threadIdx.x >> 6, lane = threadIdx.x & 63;
    const int s = blockIdx.x * 4 + wave;
    const int h = blockIdx.y;
    const int d0 = 2 * lane, d1 = 2 * lane + 1;
    const float c = cosT[s * HDIM + d0], sn = sinT[s * HDIM + d0];
    const float* r0 = qkv + (size_t)s * NQKV + h * HDIM;
    const float* r1 = r0 + (size_t)S_LEN * NQKV;
    // Q
    {
        float x0 = r0[d0] + bq[h * HDIM + d0];
        float x1 = r0[d1] + bq[h * HDIM + d1];
        if (NSEG == 2) { x0 += r1[d0]; x1 += r1[d1]; }
        float ss = x0 * x0 + x1 * x1;
        for (int m = 1; m < 64; m <<= 1) ss += __shfl_xor(ss, m);
        float r = rsqrtf(ss * (1.0f / 128.0f) + 1e-6f);
        x0 *= r * nw_q[d0]; x1 *= r * nw_q[d1];
        float o0 = (x0 * c - x1 * sn) * QSCALE;
        float o1 = (x1 * c + x0 * sn) * QSCALE;
        u32 p = (u32)f2bf(o0) | ((u32)f2bf(o1) << 16);
        *(u32*)&Qb[((size_t)h * S_LEN + s) * HDIM + d0] = p;
    }
    // K
    {
        float x0 = r0[3072 + d0] + bk[h * HDIM + d0];
        float x1 = r0[3072 + d1] + bk[h * HDIM + d1];
        if (NSEG == 2) { x0 += r1[3072 + d0]; x1 += r1[3072 + d1]; }
        float ss = x0 * x0 + x1 * x1;
        for (int m = 1; m < 64; m <<= 1) ss += __shfl_xor(ss, m);
        float r = rsqrtf(ss * (1.0f / 128.0f) + 1e-6f);
        x0 *= r * nw_k[d0]; x1 *= r * nw_k[d1];
        float o0 = x0 * c - x1 * sn;
        float o1 = x1 * c + x0 * sn;
        u32 p = (u32)f2bf(o0) | ((u32)f2bf(o1) << 16);
        *(u32*)&Kb[((size_t)h * S_LEN + s) * HDIM + d0] = p;
    }
    // V (transposed)
    {
        float v0 = r0[6144 + d0] + bv[h * HDIM + d0];
        float v1 = r0[6144 + d1] + bv[h * HDIM + d1];
        if (NSEG == 2) { v0 += r1[6144 + d0]; v1 += r1[6144 + d1]; }
        Vt[((size_t)h * HDIM + d0) * S_LEN + s] = f2bf(v0);
        Vt[((size_t)h * HDIM + d1) * S_LEN + s] = f2bf(v1);
    }
}

// ---------------- flash attention (no mask, fixed-max softmax) ----------------
__global__ __launch_bounds__(256, 2) void k_attn(const u16* __restrict__ Qb, const u16* __restrict__ Kb,
                                                 const u16* __restrict__ Vt, float* __restrict__ out) {
    __shared__ __align__(16) u16 Ks[2][64 * 128];   // [key][d], chunk ^= row&15
    __shared__ __align__(16) u16 Vs[2][128 * 64];   // [d][key], chunk ^= row&7
    __shared__ __align__(16) u16 Ps[4][32 * 64];    // per-wave P, chunk ^= row&7
    const int wave = threadIdx.x >> 6, lane = threadIdx.x & 63;
    const int wg = (blockIdx.x & 7) * 48 + (blockIdx.x >> 3);
    const int h = wg >> 4, qb = wg & 15;
    const int frow = lane & 15, fk = lane >> 4;

    short8 qf[2][4];
#pragma unroll
    for (int qg = 0; qg < 2; ++qg) {
        const u16* qbase = Qb + ((size_t)h * S_LEN + qb * 128 + wave * 32 + qg * 16 + frow) * HDIM + fk * 8;
#pragma unroll
        for (int ks = 0; ks < 4; ++ks) qf[qg][ks] = *(const short8*)(qbase + ks * 32);
    }

    f32x4 o[2][8] = {};
    float l_p[2][4] = {};

#define STAGE(buf, kt)                                                                       \
    {                                                                                        \
        _Pragma("unroll") for (int c = 0; c < 4; ++c) {                                      \
            int fi = (wave * 4 + c) * 64 + lane;                                             \
            {                                                                                \
                int r = fi >> 4, ch = fi & 15;                                               \
                lds16(Ks[buf] + (wave * 4 + c) * 512,                                        \
                      Kb + ((size_t)h * S_LEN + (kt) * 64 + r) * HDIM + ((ch ^ (r & 15)) * 8)); \
            }                                                                                \
            {                                                                                \
                int r = fi >> 3, ch = fi & 7;                                                \
                lds16(Vs[buf] + (wave * 4 + c) * 512,                                        \
                      Vt + ((size_t)h * HDIM + r) * S_LEN + (kt) * 64 + ((ch ^ (r & 7)) * 8)); \
            }                                                                                \
        }                                                                                    \
    }

    STAGE(0, 0);
    __syncthreads();
    int cur = 0;

    for (int kt = 0; kt < S_LEN / 64; ++kt) {
        if (kt + 1 < S_LEN / 64) STAGE(cur ^ 1, kt + 1);
        f32x4 sacc[2][4] = {};
#pragma unroll
        for (int nf = 0; nf < 4; ++nf) {
#pragma unroll
            for (int ks = 0; ks < 4; ++ks) {
                short8 kf = *(const short8*)&Ks[cur][(nf * 16 + frow) * 128 + (((ks * 4 + fk) ^ frow) & 15) * 8];
#pragma unroll
                for (int qg = 0; qg < 2; ++qg)
                    sacc[qg][nf] = __builtin_amdgcn_mfma_f32_16x16x32_bf16(qf[qg][ks], kf, sacc[qg][nf], 0, 0, 0);
            }
        }
#pragma unroll
        for (int qg = 0; qg < 2; ++qg)
#pragma unroll
            for (int nf = 0; nf < 4; ++nf)
#pragma unroll
                for (int i = 0; i < 4; ++i) {
                    float p = __expf(sacc[qg][nf][i] - FMAX);
                    l_p[qg][i] += p;
                    int row = qg * 16 + fk * 4 + i, col = nf * 16 + frow;
                    Ps[wave][row * 64 + (((col >> 3) ^ (row & 7)) << 3) + (col & 7)] = f2bf(p);
                }
#pragma unroll
        for (int ks = 0; ks < 2; ++ks) {
            short8 pf[2];
#pragma unroll
            for (int qg = 0; qg < 2; ++qg)
                pf[qg] = *(const short8*)&Ps[wave][(qg * 16 + frow) * 64 + (((ks * 4 + fk) ^ (frow & 7)) & 7) * 8];
#pragma unroll
            for (int nf8 = 0; nf8 < 8; ++nf8) {
                short8 vf = *(const short8*)&Vs[cur][(nf8 * 16 + frow) * 64 + (((ks * 4 + fk) ^ (frow & 7)) & 7) * 8];
#pragma unroll
                for (int qg = 0; qg < 2; ++qg)
                    o[qg][nf8] = __builtin_amdgcn_mfma_f32_16x16x32_bf16(pf[qg], vf, o[qg][nf8], 0, 0, 0);
            }
        }
        __syncthreads();
        cur ^= 1;
    }
#undef STAGE

#pragma unroll
    for (int msk = 1; msk < 16; msk <<= 1)
#pragma unroll
        for (int qg = 0; qg < 2; ++qg)
#pragma unroll
            for (int i = 0; i < 4; ++i) l_p[qg][i] += __shfl_xor(l_p[qg][i], msk);

#pragma unroll
    for (int qg = 0; qg < 2; ++qg)
#pragma unroll
        for (int nf8 = 0; nf8 < 8; ++nf8)
#pragma unroll
            for (int i = 0; i < 4; ++i) {
                int srow = qb * 128 + wave * 32 + qg * 16 + fk * 4 + i;
                out[(size_t)srow * DIMSZ + h * HDIM + nf8 * 16 + frow] = o[qg][nf8][i] / l_p[qg][i];
            }
}

// ---------------- launch ----------------
extern "C" void kernel_launch(void* const* d_in, const int* in_sizes, int n_in,
                              void* d_out, int out_size, void* d_ws, size_t ws_size,
                              hipStream_t stream) {
    const float* hs = (const float*)d_in[0];
    const float* wq = (const float*)d_in[1];
    const float* bq = (const float*)d_in[2];
    const float* wk = (const float*)d_in[3];
    const float* bk = (const float*)d_in[4];
    const float* wv = (const float*)d_in[5];
    const float* bv = (const float*)d_in[6];
    const float* nq = (const float*)d_in[7];
    const float* nk = (const float*)d_in[8];
    const float* cosT = (const float*)d_in[9];
    const float* sinT = (const float*)d_in[10];
    float* out = (float*)d_out;

    char* ws = (char*)d_ws;
    const size_t HS_B = 12582912, W_B = 56623104, QKV1 = 75497472, QKV2 = 150994944, QKVT = 37748736;
    const bool split = ws_size >= HS_B + W_B + QKV2 + QKVT; // 257,949,696 B
    u16* hs_b = (u16*)(ws);
    u16* w_b = (u16*)(ws + HS_B);
    float* qkv = (float*)(ws + HS_B + W_B);
    char* tail = ws + HS_B + W_B + (split ? QKV2 : QKV1);
    u16* Qb = (u16*)(tail);
    u16* Kb = (u16*)(tail + 12582912);
    u16* Vt = (u16*)(tail + 25165824);

    k_f2bf4<<<6144, 256, 0, stream>>>((const float4*)hs, hs_b, 1572864);
    k_f2bf4<<<9216, 256, 0, stream>>>((const float4*)wq, w_b, 2359296);
    k_f2bf4<<<9216, 256, 0, stream>>>((const float4*)wk, w_b + 9437184, 2359296);
    k_f2bf4<<<9216, 256, 0, stream>>>((const float4*)wv, w_b + 18874368, 2359296);

    if (split) {
        k_gemm<2><<<dim3(576), 512, 0, stream>>>(hs_b, w_b, qkv);
        k_post<2><<<dim3(512, 24), 256, 0, stream>>>(qkv, nq, nk, bq, bk, bv, cosT, sinT, Qb, Kb, Vt);
    } else {
        k_gemm<1><<<dim3(288), 512, 0, stream>>>(hs_b, w_b, qkv);
        k_post<1><<<dim3(512, 24), 256, 0, stream>>>(qkv, nq, nk, bq, bk, bv, cosT, sinT, Qb, Kb, Vt);
    }

    k_attn<<<dim3(384), 256, 0, stream>>>(Qb, Kb, Vt, out);
}

// Round 5
// 318.732 us; speedup vs baseline: 1.1101x; 1.1045x over previous
//
#include <hip/hip_runtime.h>

#define S_LEN 2048
#define DIMSZ 3072
#define NHEAD 24
#define HDIM 128
#define NQKV 9216
#define QSCALE 0.08838834764831845f
#define FMAX 12.0f

typedef unsigned short u16;
typedef unsigned int u32;
typedef __attribute__((ext_vector_type(8))) short short8;
typedef __attribute__((ext_vector_type(4))) float f32x4;

__device__ __forceinline__ u16 f2bf(float f) {
    u32 u = __float_as_uint(f);
    u32 r = (u + 0x7fffu + ((u >> 16) & 1u)) >> 16;
    return (u16)r;
}
__device__ __forceinline__ float bf2f(u16 u) {
    return __uint_as_float((u32)u << 16);
}

__device__ __forceinline__ void lds16(u16* lds, const u16* g) {
    __builtin_amdgcn_global_load_lds((const __attribute__((address_space(1))) u32*)g,
                                     (__attribute__((address_space(3))) u32*)lds, 16, 0, 0);
}

// ---------------- conversion kernels ----------------
__global__ void k_f2bf4(const float4* __restrict__ src, u16* __restrict__ dst, int n4) {
    int i = blockIdx.x * blockDim.x + threadIdx.x;
    if (i >= n4) return;
    float4 v = src[i];
    u32 lo = (u32)f2bf(v.x) | ((u32)f2bf(v.y) << 16);
    u32 hi = (u32)f2bf(v.z) | ((u32)f2bf(v.w) << 16);
    uint2 p; p.x = lo; p.y = hi;
    *(uint2*)(dst + (size_t)i * 4) = p;
}

// ---------------- QKV GEMM: C[m][n] = sum_k A[m][k]*W[n][k], C in bf16 ----------------
// Tile 256x288 -> grid 8x32 = 256 blocks = 1/CU, ONE round (no makespan quantization).
// 8 waves as 4M x 2N; wave = 64 rows x 144 cols = acc[4][9] f32x4 (144 VGPR).
// B tile padded to 320 rows (source row clamped) so staging = uniform 5 instr/thread
// -> wave-uniform counted vmcnt(9). Stage T+2 at tile end (after all reads of buf).
__global__ __launch_bounds__(512, 1) void k_gemm(const u16* __restrict__ A, const u16* __restrict__ W,
                                                 u16* __restrict__ C) {
    __shared__ __align__(16) u16 As[2][256 * 64]; // 32 KB each
    __shared__ __align__(16) u16 Bs[2][320 * 64]; // 40 KB each (rows 288-319 = pad)
    const int tid = threadIdx.x, wave = tid >> 6, lane = tid & 63;
    const int bm = blockIdx.x & 7, bn = blockIdx.x >> 3; // bm tied to XCD: A-panel L2-resident
    const int wm = wave >> 1, wn = wave & 1;             // 4M x 2N
    const int frow = lane & 15, fk = lane >> 4;
    const u16* baseA = A + (size_t)(bm * 256) * DIMSZ;
    const u16* baseW = W + (size_t)(bn * 288) * DIMSZ;

    auto stageA = [&](int b, int kt) { // 4 instr/thread
#pragma unroll
        for (int j = 0; j < 4; ++j) {
            int flat = j * 512 + tid, row = flat >> 3, ch = flat & 7;
            lds16(&As[b][flat * 8], baseA + (size_t)row * DIMSZ + kt * 64 + ((ch ^ (row & 7)) * 8));
        }
    };
    auto stageB = [&](int b, int kt) { // 5 instr/thread (320 padded rows, clamped source)
#pragma unroll
        for (int j = 0; j < 5; ++j) {
            int flat = j * 512 + tid, row = flat >> 3, ch = flat & 7;
            int srow = bn * 288 + row;
            srow = (srow > NQKV - 1) ? (NQKV - 1) : srow;
            lds16(&Bs[b][flat * 8], W + (size_t)srow * DIMSZ + kt * 64 + ((ch ^ (row & 7)) * 8));
        }
    };

    // prologue: tiles 0,1 (9 loads each)
    stageA(0, 0); stageB(0, 0); stageA(1, 1); stageB(1, 1);
    asm volatile("s_waitcnt vmcnt(9)"); // tile 0 landed
    __builtin_amdgcn_s_barrier();

    f32x4 acc[4][9] = {};
    for (int T = 0; T < 48; ++T) {
        const int b = T & 1;
        const u16* LA = As[b];
        const u16* LB = Bs[b];
        short8 af[4][2];
        // ---- phase 0: read all A frags + B(nf0-2); MFMA nf0-2 ----
#pragma unroll
        for (int mf = 0; mf < 4; ++mf) {
            int lrow = wm * 64 + mf * 16 + frow;
#pragma unroll
            for (int ks = 0; ks < 2; ++ks)
                af[mf][ks] = *(const short8*)&LA[lrow * 64 + (((ks * 4 + fk) ^ (frow & 7)) * 8)];
        }
#pragma unroll
        for (int ph = 0; ph < 3; ++ph) {
            short8 bf[3][2];
#pragma unroll
            for (int j = 0; j < 3; ++j) {
                int nf = ph * 3 + j;
                int lrow = wn * 144 + nf * 16 + frow;
#pragma unroll
                for (int ks = 0; ks < 2; ++ks)
                    bf[j][ks] = *(const short8*)&LB[lrow * 64 + (((ks * 4 + fk) ^ (frow & 7)) * 8)];
            }
            __builtin_amdgcn_s_barrier();
            __builtin_amdgcn_s_setprio(1);
#pragma unroll
            for (int mf = 0; mf < 4; ++mf)
#pragma unroll
                for (int j = 0; j < 3; ++j)
#pragma unroll
                    for (int ks = 0; ks < 2; ++ks)
                        acc[mf][ph * 3 + j] =
                            __builtin_amdgcn_mfma_f32_16x16x32_bf16(af[mf][ks], bf[j][ks], acc[mf][ph * 3 + j], 0, 0, 0);
            __builtin_amdgcn_s_setprio(0);
            __builtin_amdgcn_s_barrier();
        }
        // ---- tile end: stage T+2 into this (now fully-read) buffer; counted wait ----
        if (T < 46) {
            stageB(b, T + 2);
            stageA(b, T + 2);
            asm volatile("s_waitcnt vmcnt(9)"); // tile T+1's 9 loads landed
            __builtin_amdgcn_s_barrier();
        } else if (T == 46) {
            asm volatile("s_waitcnt vmcnt(0)"); // tail drain for tile 47
            __builtin_amdgcn_s_barrier();
        }
    }

    // epilogue: bf16 C
#pragma unroll
    for (int mf = 0; mf < 4; ++mf) {
#pragma unroll
        for (int nf = 0; nf < 9; ++nf) {
            int n = bn * 288 + wn * 144 + nf * 16 + frow;
#pragma unroll
            for (int i = 0; i < 4; ++i) {
                int m = bm * 256 + wm * 64 + mf * 16 + fk * 4 + i;
                C[(size_t)m * NQKV + n] = f2bf(acc[mf][nf][i]);
            }
        }
    }
}

// ---------------- postprocess: bias + RMSNorm + RoPE + layout (reads bf16 qkv) --------
__global__ void k_post(const u16* __restrict__ qkv, const float* __restrict__ nw_q,
                       const float* __restrict__ nw_k, const float* __restrict__ bq,
                       const float* __restrict__ bk, const float* __restrict__ bv,
                       const float* __restrict__ cosT, const float* __restrict__ sinT,
                       u16* __restrict__ Qb, u16* __restrict__ Kb, u16* __restrict__ Vt) {
    const int wave = threadIdx.x >> 6, lane = threadIdx.x & 63;
    const int s = blockIdx.x * 4 + wave;
    const int h = blockIdx.y;
    const int d0 = 2 * lane, d1 = 2 * lane + 1;
    const float c = cosT[s * HDIM + d0], sn = sinT[s * HDIM + d0];
    const u16* r0 = qkv + (size_t)s * NQKV + h * HDIM;
    // Q
    {
        float x0 = bf2f(r0[d0]) + bq[h * HDIM + d0];
        float x1 = bf2f(r0[d1]) + bq[h * HDIM + d1];
        float ss = x0 * x0 + x1 * x1;
        for (int m = 1; m < 64; m <<= 1) ss += __shfl_xor(ss, m);
        float r = rsqrtf(ss * (1.0f / 128.0f) + 1e-6f);
        x0 *= r * nw_q[d0]; x1 *= r * nw_q[d1];
        float o0 = (x0 * c - x1 * sn) * QSCALE;
        float o1 = (x1 * c + x0 * sn) * QSCALE;
        u32 p = (u32)f2bf(o0) | ((u32)f2bf(o1) << 16);
        *(u32*)&Qb[((size_t)h * S_LEN + s) * HDIM + d0] = p;
    }
    // K
    {
        float x0 = bf2f(r0[3072 + d0]) + bk[h * HDIM + d0];
        float x1 = bf2f(r0[3072 + d1]) + bk[h * HDIM + d1];
        float ss = x0 * x0 + x1 * x1;
        for (int m = 1; m < 64; m <<= 1) ss += __shfl_xor(ss, m);
        float r = rsqrtf(ss * (1.0f / 128.0f) + 1e-6f);
        x0 *= r * nw_k[d0]; x1 *= r * nw_k[d1];
        float o0 = x0 * c - x1 * sn;
        float o1 = x1 * c + x0 * sn;
        u32 p = (u32)f2bf(o0) | ((u32)f2bf(o1) << 16);
        *(u32*)&Kb[((size_t)h * S_LEN + s) * HDIM + d0] = p;
    }
    // V (transposed)
    {
        float v0 = bf2f(r0[6144 + d0]) + bv[h * HDIM + d0];
        float v1 = bf2f(r0[6144 + d1]) + bv[h * HDIM + d1];
        Vt[((size_t)h * HDIM + d0) * S_LEN + s] = f2bf(v0);
        Vt[((size_t)h * HDIM + d1) * S_LEN + s] = f2bf(v1);
    }
}

// ---------------- flash attention (no mask, fixed-max softmax) ----------------
__global__ __launch_bounds__(256, 2) void k_attn(const u16* __restrict__ Qb, const u16* __restrict__ Kb,
                                                 const u16* __restrict__ Vt, float* __restrict__ out) {
    __shared__ __align__(16) u16 Ks[2][64 * 128];   // [key][d], chunk ^= row&15
    __shared__ __align__(16) u16 Vs[2][128 * 64];   // [d][key], chunk ^= row&7
    __shared__ __align__(16) u16 Ps[4][32 * 64];    // per-wave P, chunk ^= row&7
    const int wave = threadIdx.x >> 6, lane = threadIdx.x & 63;
    const int wg = (blockIdx.x & 7) * 48 + (blockIdx.x >> 3);
    const int h = wg >> 4, qb = wg & 15;
    const int frow = lane & 15, fk = lane >> 4;

    short8 qf[2][4];
#pragma unroll
    for (int qg = 0; qg < 2; ++qg) {
        const u16* qbase = Qb + ((size_t)h * S_LEN + qb * 128 + wave * 32 + qg * 16 + frow) * HDIM + fk * 8;
#pragma unroll
        for (int ks = 0; ks < 4; ++ks) qf[qg][ks] = *(const short8*)(qbase + ks * 32);
    }

    f32x4 o[2][8] = {};
    float l_p[2][4] = {};

#define STAGE(buf, kt)                                                                       \
    {                                                                                        \
        _Pragma("unroll") for (int c = 0; c < 4; ++c) {                                      \
            int fi = (wave * 4 + c) * 64 + lane;                                             \
            {                                                                                \
                int r = fi >> 4, ch = fi & 15;                                               \
                lds16(Ks[buf] + (wave * 4 + c) * 512,                                        \
                      Kb + ((size_t)h * S_LEN + (kt) * 64 + r) * HDIM + ((ch ^ (r & 15)) * 8)); \
            }                                                                                \
            {                                                                                \
                int r = fi >> 3, ch = fi & 7;                                                \
                lds16(Vs[buf] + (wave * 4 + c) * 512,                                        \
                      Vt + ((size_t)h * HDIM + r) * S_LEN + (kt) * 64 + ((ch ^ (r & 7)) * 8)); \
            }                                                                                \
        }                                                                                    \
    }

    STAGE(0, 0);
    __syncthreads();
    int cur = 0;

    for (int kt = 0; kt < S_LEN / 64; ++kt) {
        if (kt + 1 < S_LEN / 64) STAGE(cur ^ 1, kt + 1);
        f32x4 sacc[2][4] = {};
#pragma unroll
        for (int nf = 0; nf < 4; ++nf) {
#pragma unroll
            for (int ks = 0; ks < 4; ++ks) {
                short8 kf = *(const short8*)&Ks[cur][(nf * 16 + frow) * 128 + (((ks * 4 + fk) ^ frow) & 15) * 8];
#pragma unroll
                for (int qg = 0; qg < 2; ++qg)
                    sacc[qg][nf] = __builtin_amdgcn_mfma_f32_16x16x32_bf16(qf[qg][ks], kf, sacc[qg][nf], 0, 0, 0);
            }
        }
#pragma unroll
        for (int qg = 0; qg < 2; ++qg)
#pragma unroll
            for (int nf = 0; nf < 4; ++nf)
#pragma unroll
                for (int i = 0; i < 4; ++i) {
                    float p = __expf(sacc[qg][nf][i] - FMAX);
                    l_p[qg][i] += p;
                    int row = qg * 16 + fk * 4 + i, col = nf * 16 + frow;
                    Ps[wave][row * 64 + (((col >> 3) ^ (row & 7)) << 3) + (col & 7)] = f2bf(p);
                }
#pragma unroll
        for (int ks = 0; ks < 2; ++ks) {
            short8 pf[2];
#pragma unroll
            for (int qg = 0; qg < 2; ++qg)
                pf[qg] = *(const short8*)&Ps[wave][(qg * 16 + frow) * 64 + (((ks * 4 + fk) ^ (frow & 7)) & 7) * 8];
#pragma unroll
            for (int nf8 = 0; nf8 < 8; ++nf8) {
                short8 vf = *(const short8*)&Vs[cur][(nf8 * 16 + frow) * 64 + (((ks * 4 + fk) ^ (frow & 7)) & 7) * 8];
#pragma unroll
                for (int qg = 0; qg < 2; ++qg)
                    o[qg][nf8] = __builtin_amdgcn_mfma_f32_16x16x32_bf16(pf[qg], vf, o[qg][nf8], 0, 0, 0);
            }
        }
        __syncthreads();
        cur ^= 1;
    }
#undef STAGE

#pragma unroll
    for (int msk = 1; msk < 16; msk <<= 1)
#pragma unroll
        for (int qg = 0; qg < 2; ++qg)
#pragma unroll
            for (int i = 0; i < 4; ++i) l_p[qg][i] += __shfl_xor(l_p[qg][i], msk);

#pragma unroll
    for (int qg = 0; qg < 2; ++qg)
#pragma unroll
        for (int nf8 = 0; nf8 < 8; ++nf8)
#pragma unroll
            for (int i = 0; i < 4; ++i) {
                int srow = qb * 128 + wave * 32 + qg * 16 + fk * 4 + i;
                out[(size_t)srow * DIMSZ + h * HDIM + nf8 * 16 + frow] = o[qg][nf8][i] / l_p[qg][i];
            }
}

// ---------------- launch ----------------
extern "C" void kernel_launch(void* const* d_in, const int* in_sizes, int n_in,
                              void* d_out, int out_size, void* d_ws, size_t ws_size,
                              hipStream_t stream) {
    const float* hs = (const float*)d_in[0];
    const float* wq = (const float*)d_in[1];
    const float* bq = (const float*)d_in[2];
    const float* wk = (const float*)d_in[3];
    const float* bk = (const float*)d_in[4];
    const float* wv = (const float*)d_in[5];
    const float* bv = (const float*)d_in[6];
    const float* nq = (const float*)d_in[7];
    const float* nk = (const float*)d_in[8];
    const float* cosT = (const float*)d_in[9];
    const float* sinT = (const float*)d_in[10];
    float* out = (float*)d_out;

    char* ws = (char*)d_ws;
    const size_t HS_B = 12582912, W_B = 56623104, QKV_B = 37748736;
    u16* hs_b = (u16*)(ws);
    u16* w_b = (u16*)(ws + HS_B);
    u16* qkv = (u16*)(ws + HS_B + W_B);
    char* tail = ws + HS_B + W_B + QKV_B;
    u16* Qb = (u16*)(tail);
    u16* Kb = (u16*)(tail + 12582912);
    u16* Vt = (u16*)(tail + 25165824); // total 144,703,488 B

    k_f2bf4<<<6144, 256, 0, stream>>>((const float4*)hs, hs_b, 1572864);
    k_f2bf4<<<9216, 256, 0, stream>>>((const float4*)wq, w_b, 2359296);
    k_f2bf4<<<9216, 256, 0, stream>>>((const float4*)wk, w_b + 9437184, 2359296);
    k_f2bf4<<<9216, 256, 0, stream>>>((const float4*)wv, w_b + 18874368, 2359296);

    // QKV projection: 256 blocks (8 bm x 32 bn), exactly 1 block/CU, one round
    k_gemm<<<dim3(256), 512, 0, stream>>>(hs_b, w_b, qkv);

    k_post<<<dim3(512, 24), 256, 0, stream>>>(qkv, nq, nk, bq, bk, bv, cosT, sinT, Qb, Kb, Vt);

    k_attn<<<dim3(384), 256, 0, stream>>>(Qb, Kb, Vt, out);
}

// Round 6
// 310.168 us; speedup vs baseline: 1.1407x; 1.0276x over previous
//
#include <hip/hip_runtime.h>

#define S_LEN 2048
#define DIMSZ 3072
#define NHEAD 24
#define HDIM 128
#define NQKV 9216
#define QSCALE 0.08838834764831845f
#define FMAX 12.0f

typedef unsigned short u16;
typedef unsigned int u32;
typedef __attribute__((ext_vector_type(8))) short short8;
typedef __attribute__((ext_vector_type(4))) float f32x4;

__device__ __forceinline__ u16 f2bf(float f) {
    u32 u = __float_as_uint(f);
    u32 r = (u + 0x7fffu + ((u >> 16) & 1u)) >> 16;
    return (u16)r;
}
__device__ __forceinline__ float bf2f(u16 u) {
    return __uint_as_float((u32)u << 16);
}

__device__ __forceinline__ void lds16(u16* lds, const u16* g) {
    __builtin_amdgcn_global_load_lds((const __attribute__((address_space(1))) u32*)g,
                                     (__attribute__((address_space(3))) u32*)lds, 16, 0, 0);
}

// ---------------- conversion kernels ----------------
__global__ void k_f2bf4(const float4* __restrict__ src, u16* __restrict__ dst, int n4) {
    int i = blockIdx.x * blockDim.x + threadIdx.x;
    if (i >= n4) return;
    float4 v = src[i];
    u32 lo = (u32)f2bf(v.x) | ((u32)f2bf(v.y) << 16);
    u32 hi = (u32)f2bf(v.z) | ((u32)f2bf(v.w) << 16);
    uint2 p; p.x = lo; p.y = hi;
    *(uint2*)(dst + (size_t)i * 4) = p;
}

// ---------------- QKV GEMM: C[m][n] = sum_k A[m][k]*W[n][k], C bf16 ----------------
// Tile 256x144, BK=32 -> grid 8x64 = 512 blocks = exactly 2/CU (one dispatch round).
// 4 waves (256 thr), wave = 64 rows x 144 cols = acc[4][9]. LDS 56 KB -> 2 blocks/CU:
// the co-resident block provides MFMA/LDS/VMEM overlap (TLP), no lockstep coupling.
// Per tile: 13 ds_read_b128 + 36 MFMA per wave, 3 barriers. Stage T+2 into the
// just-consumed buffer after the MFMA-closing barrier; counted vmcnt(7) per tile.
__global__ __launch_bounds__(256, 2) void k_gemm(const u16* __restrict__ A, const u16* __restrict__ W,
                                                 u16* __restrict__ C) {
    __shared__ __align__(16) u16 As[2][256 * 32]; // 16 KB each
    __shared__ __align__(16) u16 Bs[2][192 * 32]; // 12 KB each (rows 144-191 = pad)
    const int tid = threadIdx.x, wave = tid >> 6, lane = tid & 63;
    const int bm = blockIdx.x & 7, bn = blockIdx.x >> 3; // bm tied to XCD: A panel L2-resident
    const int frow = lane & 15, fk = lane >> 4;
    const u16* baseA = A + (size_t)(bm * 256) * DIMSZ;

    auto stageA = [&](int b, int kt) { // 4 instr/thread, 256 rows x 32 cols
#pragma unroll
        for (int j = 0; j < 4; ++j) {
            int flat = j * 256 + tid, row = flat >> 2, ch = flat & 3;
            lds16(&As[b][flat * 8], baseA + (size_t)row * DIMSZ + kt * 32 + ((ch ^ ((row >> 1) & 3)) * 8));
        }
    };
    auto stageB = [&](int b, int kt) { // 3 instr/thread, 192 rows (clamped source)
#pragma unroll
        for (int j = 0; j < 3; ++j) {
            int flat = j * 256 + tid, row = flat >> 2, ch = flat & 3;
            int srow = bn * 144 + row;
            srow = (srow > NQKV - 1) ? (NQKV - 1) : srow;
            lds16(&Bs[b][flat * 8], W + (size_t)srow * DIMSZ + kt * 32 + ((ch ^ ((row >> 1) & 3)) * 8));
        }
    };

    // prologue: tiles 0,1 (7 loads each)
    stageA(0, 0); stageB(0, 0); stageA(1, 1); stageB(1, 1);
    asm volatile("s_waitcnt vmcnt(7)"); // tile 0's 7 landed
    __builtin_amdgcn_s_barrier();

    f32x4 acc[4][9] = {};
    for (int T = 0; T < 96; ++T) {
        const int b = T & 1;
        const u16* LA = As[b];
        const u16* LB = Bs[b];
        short8 af[4], bf[9];
#pragma unroll
        for (int mf = 0; mf < 4; ++mf) {
            int row = wave * 64 + mf * 16 + frow;
            af[mf] = *(const short8*)&LA[row * 32 + ((fk ^ ((row >> 1) & 3)) * 8)];
        }
#pragma unroll
        for (int nf = 0; nf < 9; ++nf) {
            int row = nf * 16 + frow;
            bf[nf] = *(const short8*)&LB[row * 32 + ((fk ^ ((row >> 1) & 3)) * 8)];
        }
        __builtin_amdgcn_s_barrier();
        __builtin_amdgcn_s_setprio(1);
#pragma unroll
        for (int mf = 0; mf < 4; ++mf)
#pragma unroll
            for (int nf = 0; nf < 9; ++nf)
                acc[mf][nf] = __builtin_amdgcn_mfma_f32_16x16x32_bf16(af[mf], bf[nf], acc[mf][nf], 0, 0, 0);
        __builtin_amdgcn_s_setprio(0);
        __builtin_amdgcn_s_barrier(); // all reads of buf b complete past this point
        if (T < 94) {
            stageA(b, T + 2); stageB(b, T + 2);   // safe: buffer fully consumed
            asm volatile("s_waitcnt vmcnt(7)");   // tile T+1's 7 loads landed (counted)
            __builtin_amdgcn_s_barrier();         // cross-wave: everyone's T+1 landed
        } else if (T == 94) {
            asm volatile("s_waitcnt vmcnt(0)");
            __builtin_amdgcn_s_barrier();
        }
    }

    // epilogue: bf16 C
#pragma unroll
    for (int mf = 0; mf < 4; ++mf) {
#pragma unroll
        for (int nf = 0; nf < 9; ++nf) {
            int n = bn * 144 + nf * 16 + frow;
#pragma unroll
            for (int i = 0; i < 4; ++i) {
                int m = bm * 256 + wave * 64 + mf * 16 + fk * 4 + i;
                C[(size_t)m * NQKV + n] = f2bf(acc[mf][nf][i]);
            }
        }
    }
}

// ---------------- postprocess: bias + RMSNorm + RoPE + layout (reads bf16 qkv) --------
__global__ void k_post(const u16* __restrict__ qkv, const float* __restrict__ nw_q,
                       const float* __restrict__ nw_k, const float* __restrict__ bq,
                       const float* __restrict__ bk, const float* __restrict__ bv,
                       const float* __restrict__ cosT, const float* __restrict__ sinT,
                       u16* __restrict__ Qb, u16* __restrict__ Kb, u16* __restrict__ Vt) {
    const int wave = threadIdx.x >> 6, lane = threadIdx.x & 63;
    const int s = blockIdx.x * 4 + wave;
    const int h = blockIdx.y;
    const int d0 = 2 * lane, d1 = 2 * lane + 1;
    const float c = cosT[s * HDIM + d0], sn = sinT[s * HDIM + d0];
    const u16* r0 = qkv + (size_t)s * NQKV + h * HDIM;
    // Q
    {
        float x0 = bf2f(r0[d0]) + bq[h * HDIM + d0];
        float x1 = bf2f(r0[d1]) + bq[h * HDIM + d1];
        float ss = x0 * x0 + x1 * x1;
        for (int m = 1; m < 64; m <<= 1) ss += __shfl_xor(ss, m);
        float r = rsqrtf(ss * (1.0f / 128.0f) + 1e-6f);
        x0 *= r * nw_q[d0]; x1 *= r * nw_q[d1];
        float o0 = (x0 * c - x1 * sn) * QSCALE;
        float o1 = (x1 * c + x0 * sn) * QSCALE;
        u32 p = (u32)f2bf(o0) | ((u32)f2bf(o1) << 16);
        *(u32*)&Qb[((size_t)h * S_LEN + s) * HDIM + d0] = p;
    }
    // K
    {
        float x0 = bf2f(r0[3072 + d0]) + bk[h * HDIM + d0];
        float x1 = bf2f(r0[3072 + d1]) + bk[h * HDIM + d1];
        float ss = x0 * x0 + x1 * x1;
        for (int m = 1; m < 64; m <<= 1) ss += __shfl_xor(ss, m);
        float r = rsqrtf(ss * (1.0f / 128.0f) + 1e-6f);
        x0 *= r * nw_k[d0]; x1 *= r * nw_k[d1];
        float o0 = x0 * c - x1 * sn;
        float o1 = x1 * c + x0 * sn;
        u32 p = (u32)f2bf(o0) | ((u32)f2bf(o1) << 16);
        *(u32*)&Kb[((size_t)h * S_LEN + s) * HDIM + d0] = p;
    }
    // V (transposed)
    {
        float v0 = bf2f(r0[6144 + d0]) + bv[h * HDIM + d0];
        float v1 = bf2f(r0[6144 + d1]) + bv[h * HDIM + d1];
        Vt[((size_t)h * HDIM + d0) * S_LEN + s] = f2bf(v0);
        Vt[((size_t)h * HDIM + d1) * S_LEN + s] = f2bf(v1);
    }
}

// ---------------- flash attention (no mask, fixed-max softmax) ----------------
__global__ __launch_bounds__(256, 2) void k_attn(const u16* __restrict__ Qb, const u16* __restrict__ Kb,
                                                 const u16* __restrict__ Vt, float* __restrict__ out) {
    __shared__ __align__(16) u16 Ks[2][64 * 128];   // [key][d], chunk ^= row&15
    __shared__ __align__(16) u16 Vs[2][128 * 64];   // [d][key], chunk ^= row&7
    __shared__ __align__(16) u16 Ps[4][32 * 64];    // per-wave P, chunk ^= row&7
    const int wave = threadIdx.x >> 6, lane = threadIdx.x & 63;
    const int wg = (blockIdx.x & 7) * 48 + (blockIdx.x >> 3);
    const int h = wg >> 4, qb = wg & 15;
    const int frow = lane & 15, fk = lane >> 4;

    short8 qf[2][4];
#pragma unroll
    for (int qg = 0; qg < 2; ++qg) {
        const u16* qbase = Qb + ((size_t)h * S_LEN + qb * 128 + wave * 32 + qg * 16 + frow) * HDIM + fk * 8;
#pragma unroll
        for (int ks = 0; ks < 4; ++ks) qf[qg][ks] = *(const short8*)(qbase + ks * 32);
    }

    f32x4 o[2][8] = {};
    float l_p[2][4] = {};

#define STAGE(buf, kt)                                                                       \
    {                                                                                        \
        _Pragma("unroll") for (int c = 0; c < 4; ++c) {                                      \
            int fi = (wave * 4 + c) * 64 + lane;                                             \
            {                                                                                \
                int r = fi >> 4, ch = fi & 15;                                               \
                lds16(Ks[buf] + (wave * 4 + c) * 512,                                        \
                      Kb + ((size_t)h * S_LEN + (kt) * 64 + r) * HDIM + ((ch ^ (r & 15)) * 8)); \
            }                                                                                \
            {                                                                                \
                int r = fi >> 3, ch = fi & 7;                                                \
                lds16(Vs[buf] + (wave * 4 + c) * 512,                                        \
                      Vt + ((size_t)h * HDIM + r) * S_LEN + (kt) * 64 + ((ch ^ (r & 7)) * 8)); \
            }                                                                                \
        }                                                                                    \
    }

    STAGE(0, 0);
    __syncthreads();
    int cur = 0;

    for (int kt = 0; kt < S_LEN / 64; ++kt) {
        if (kt + 1 < S_LEN / 64) STAGE(cur ^ 1, kt + 1);
        f32x4 sacc[2][4] = {};
#pragma unroll
        for (int nf = 0; nf < 4; ++nf) {
#pragma unroll
            for (int ks = 0; ks < 4; ++ks) {
                short8 kf = *(const short8*)&Ks[cur][(nf * 16 + frow) * 128 + (((ks * 4 + fk) ^ frow) & 15) * 8];
#pragma unroll
                for (int qg = 0; qg < 2; ++qg)
                    sacc[qg][nf] = __builtin_amdgcn_mfma_f32_16x16x32_bf16(qf[qg][ks], kf, sacc[qg][nf], 0, 0, 0);
            }
        }
#pragma unroll
        for (int qg = 0; qg < 2; ++qg)
#pragma unroll
            for (int nf = 0; nf < 4; ++nf)
#pragma unroll
                for (int i = 0; i < 4; ++i) {
                    float p = __expf(sacc[qg][nf][i] - FMAX);
                    l_p[qg][i] += p;
                    int row = qg * 16 + fk * 4 + i, col = nf * 16 + frow;
                    Ps[wave][row * 64 + (((col >> 3) ^ (row & 7)) << 3) + (col & 7)] = f2bf(p);
                }
#pragma unroll
        for (int ks = 0; ks < 2; ++ks) {
            short8 pf[2];
#pragma unroll
            for (int qg = 0; qg < 2; ++qg)
                pf[qg] = *(const short8*)&Ps[wave][(qg * 16 + frow) * 64 + (((ks * 4 + fk) ^ (frow & 7)) & 7) * 8];
#pragma unroll
            for (int nf8 = 0; nf8 < 8; ++nf8) {
                short8 vf = *(const short8*)&Vs[cur][(nf8 * 16 + frow) * 64 + (((ks * 4 + fk) ^ (frow & 7)) & 7) * 8];
#pragma unroll
                for (int qg = 0; qg < 2; ++qg)
                    o[qg][nf8] = __builtin_amdgcn_mfma_f32_16x16x32_bf16(pf[qg], vf, o[qg][nf8], 0, 0, 0);
            }
        }
        __syncthreads();
        cur ^= 1;
    }
#undef STAGE

#pragma unroll
    for (int msk = 1; msk < 16; msk <<= 1)
#pragma unroll
        for (int qg = 0; qg < 2; ++qg)
#pragma unroll
            for (int i = 0; i < 4; ++i) l_p[qg][i] += __shfl_xor(l_p[qg][i], msk);

#pragma unroll
    for (int qg = 0; qg < 2; ++qg)
#pragma unroll
        for (int nf8 = 0; nf8 < 8; ++nf8)
#pragma unroll
            for (int i = 0; i < 4; ++i) {
                int srow = qb * 128 + wave * 32 + qg * 16 + fk * 4 + i;
                out[(size_t)srow * DIMSZ + h * HDIM + nf8 * 16 + frow] = o[qg][nf8][i] / l_p[qg][i];
            }
}

// ---------------- launch ----------------
extern "C" void kernel_launch(void* const* d_in, const int* in_sizes, int n_in,
                              void* d_out, int out_size, void* d_ws, size_t ws_size,
                              hipStream_t stream) {
    const float* hs = (const float*)d_in[0];
    const float* wq = (const float*)d_in[1];
    const float* bq = (const float*)d_in[2];
    const float* wk = (const float*)d_in[3];
    const float* bk = (const float*)d_in[4];
    const float* wv = (const float*)d_in[5];
    const float* bv = (const float*)d_in[6];
    const float* nq = (const float*)d_in[7];
    const float* nk = (const float*)d_in[8];
    const float* cosT = (const float*)d_in[9];
    const float* sinT = (const float*)d_in[10];
    float* out = (float*)d_out;

    char* ws = (char*)d_ws;
    const size_t HS_B = 12582912, W_B = 56623104, QKV_B = 37748736;
    u16* hs_b = (u16*)(ws);
    u16* w_b = (u16*)(ws + HS_B);
    u16* qkv = (u16*)(ws + HS_B + W_B);
    char* tail = ws + HS_B + W_B + QKV_B;
    u16* Qb = (u16*)(tail);
    u16* Kb = (u16*)(tail + 12582912);
    u16* Vt = (u16*)(tail + 25165824); // total 144,703,488 B

    k_f2bf4<<<6144, 256, 0, stream>>>((const float4*)hs, hs_b, 1572864);
    k_f2bf4<<<9216, 256, 0, stream>>>((const float4*)wq, w_b, 2359296);
    k_f2bf4<<<9216, 256, 0, stream>>>((const float4*)wk, w_b + 9437184, 2359296);
    k_f2bf4<<<9216, 256, 0, stream>>>((const float4*)wv, w_b + 18874368, 2359296);

    // QKV projection: 512 blocks (8 bm x 64 bn), exactly 2 blocks/CU, one round
    k_gemm<<<dim3(512), 256, 0, stream>>>(hs_b, w_b, qkv);

    k_post<<<dim3(512, 24), 256, 0, stream>>>(qkv, nq, nk, bq, bk, bv, cosT, sinT, Qb, Kb, Vt);

    k_attn<<<dim3(384), 256, 0, stream>>>(Qb, Kb, Vt, out);
}